// Round 15
// baseline (234.630 us; speedup 1.0000x reference)
//
#include <hip/hip_runtime.h>
#include <hip/hip_bf16.h>
#include <stdint.h>

#define D_MODEL 4096
#define D_BASE  8192
#define K_SUB   1024
#define N_TOK   8192

typedef __attribute__((ext_vector_type(8))) short bf16x8;
typedef __attribute__((ext_vector_type(4))) float f32x4;

__device__ __forceinline__ unsigned short f2bf(float f) {
    union { float f; uint32_t u; } c; c.f = f;
    uint32_t u = c.u;
    uint32_t r = u + 0x7FFFu + ((u >> 16) & 1u);   // round-to-nearest-even
    return (unsigned short)(r >> 16);
}

__device__ __forceinline__ void gload_lds16(const void* g, void* l) {
    __builtin_amdgcn_global_load_lds(
        (__attribute__((address_space(1))) void*)g,
        (__attribute__((address_space(3))) void*)l, 16, 0, 0);
}

#define VMCNT(N) do { __builtin_amdgcn_sched_barrier(0); \
    asm volatile("s_waitcnt vmcnt(" #N ")" ::: "memory"); } while (0)
#define PHASE_MID() do { __builtin_amdgcn_sched_barrier(0); __builtin_amdgcn_s_barrier(); \
    asm volatile("s_waitcnt lgkmcnt(0)" ::: "memory"); __builtin_amdgcn_sched_barrier(0); } while (0)
#define PHASE_END() do { __builtin_amdgcn_sched_barrier(0); __builtin_amdgcn_s_barrier(); } while (0)

// ---------------- Prep: gathers ONLY (no convert pass — fused into GEMM1) ------
//   b in [0,2048):     gather_u — 8 k-rows x 256 n per block, pure reg form
//   b in [2048,3072):  gather_v — 64x64 LDS transpose (R6-proven)
__global__ __launch_bounds__(256) void gathers_k(const int* __restrict__ idx,
                                                 const float* __restrict__ U,
                                                 const float* __restrict__ V,
                                                 unsigned short* __restrict__ Ut,
                                                 unsigned short* __restrict__ Vt) {
    __shared__ __align__(16) char smem[8704];
    const int b = blockIdx.x;
    const int t = threadIdx.x;
    if (b < 2048) {
        const int n0 = (b & 3) * 256;
        const int k0 = (b >> 2) * 8;
        const int n = n0 + t;
        const int col = idx[n];
        const float* Ucol = U + (size_t)k0 * D_BASE + col;
        unsigned short v[8];
        #pragma unroll
        for (int kr = 0; kr < 8; ++kr)
            v[kr] = f2bf(Ucol[(size_t)kr * D_BASE]);
        ushort4 a, q;
        a.x = v[0]; a.y = v[1]; a.z = v[2]; a.w = v[3];
        q.x = v[4]; q.y = v[5]; q.z = v[6]; q.w = v[7];
        *(ushort4*)(Ut + (size_t)n * D_MODEL + k0) = a;
        *(ushort4*)(Ut + (size_t)n * D_MODEL + k0 + 4) = q;
    } else {
        unsigned short (*tile)[66] = (unsigned short(*)[66])smem;   // 64x66
        int* lidx = (int*)(smem + 64 * 66 * 2);
        const int bx = b - 2048;
        const int n0 = (bx & 15) * 64;
        const int d0 = (bx >> 4) * 64;
        if (t < 64) lidx[t] = idx[n0 + t];
        __syncthreads();
        const int c = t & 63, r4 = t >> 6;
        #pragma unroll
        for (int p = 0; p < 16; ++p) {
            int nr = p * 4 + r4;
            tile[nr][c] = f2bf(V[(size_t)lidx[nr] * D_MODEL + d0 + c]);
        }
        __syncthreads();
        #pragma unroll
        for (int p = 0; p < 16; ++p) {
            int dr = p * 4 + r4;
            Vt[(size_t)(d0 + dr) * K_SUB + n0 + c] = tile[c][dr];
        }
    }
}

// ---------------- GEMM1: P = silu(x @ Usub), A = f32 staged directly ----------------
// M=8192 N=1024 K=4096. BM=128 BN=256 BK=64, 8 waves 2M x 4N -> wave 64x64.
// A: x staged AS F32 via global_load_lds (fire-and-forget, NO reg round-trip —
//    the R5/R13 trap), converted f32->bf16 at LDS-read time (64 f2bf/wave/K-tile,
//    negligible vs K-tile budget). Kills the 192 MB convert_k pass entirely.
// A LDS rows = 64 f32 = 16 granules(16B); swizzle g^(row&15): 16 lanes (rows
//    m*16+lr) hit 16 distinct granule slots -> 2-way bank alias only (free).
// B: bf16 global_load_lds as before (8-granule rows, g^(row&7) swizzle).
// LDS 128 KB: A f32 2x32KB | B 2x32KB.
// Ledger (2 phases/K-tile): p0 reads af(kt)+B01(kt), stages B[kt+1] (4 vm);
// p1 reads B23(kt), stages A[kt+2] (4 vm), end-p1 VMCNT(4) (drains A[kt+1](4)+
// B[kt+1](4), leaves A[kt+2]). Prologue: A[0](4),B[0](4),A[1](4) -> VMCNT(4).
// Overwrite safety: A slots (parity kt) last read p0(kt), overwritten p1(kt)
// (1 barrier later); B slots (parity^1) last read p1(kt-1), overwritten p0(kt).
__global__ __launch_bounds__(512, 2)
void gemm1_f32a(const float* __restrict__ X, const unsigned short* __restrict__ Bt,
                unsigned short* __restrict__ C) {
    constexpr int K = D_MODEL, N = K_SUB, NT = K / 64;   // NT=64
    __shared__ __align__(16) unsigned short lds[65536];  // 128 KB

    const int t = threadIdx.x, lane = t & 63, w = t >> 6;
    const int wm = w >> 2, wn = w & 3;                   // 2M x 4N
    const int lr = lane & 15, lk = lane >> 4;

    // XCD swizzle: 256 blocks; per XCD 32 consecutive g = 8 mb x 4 nb
    const int f = blockIdx.x;
    const int g = (f & 7) * 32 + (f >> 3);
    const int m0 = (g >> 2) * 128, n0 = (g & 3) * 256;

    // B swizzle (8-granule bf16 rows)
    const int cswz0 = ((lk ^ (lr & 7)) * 8);
    const int cswz1 = (((4 + lk) ^ (lr & 7)) * 8);
    const int srow = lane >> 3;                          // B stage: row in 8-chunk
    const int scol = ((lane & 7) ^ srow) * 8;
    // A stage: per 16-granule chunk of 4 rows
    const int ar4 = lane >> 4;                           // row in 4-chunk
    const int ag = lane & 15;                            // dest granule

    // A region: ushort offset (kt&1)*16384 + half*8192  (32KB per buf)
    auto stage_A = [&](int kt, int half) {
        const float* src = X + (size_t)(m0 + half * 64) * K + kt * 64;
        unsigned short* dst = &lds[(kt & 1) * 16384 + half * 8192];
        #pragma unroll
        for (int i = 0; i < 2; ++i) {
            int c2 = i * 8 + w;                          // 16 chunks of 4 rows
            int rl = c2 * 4 + ar4;                       // row in half [0,64)
            int gsw = ag ^ (rl & 15);                    // pre-swizzled source granule
            gload_lds16(src + (size_t)rl * K + gsw * 4, dst + c2 * 512);
        }
    };
    // B region: ushort offset 32768 + (kt&1)*16384 + nh*8192
    auto stage_B = [&](int kt, int nh) {
        const unsigned short* src = Bt + (size_t)(n0 + nh * 128) * K + kt * 64;
        unsigned short* dst = &lds[32768 + (kt & 1) * 16384 + nh * 8192];
        #pragma unroll
        for (int i = 0; i < 2; ++i) {
            int c2 = i * 8 + w;
            gload_lds16(src + (size_t)(c2 * 8 + srow) * K + scol, dst + c2 * 512);
        }
    };
    auto read_A = [&](int kt, bf16x8 (&af)[4][2]) {
        const float* base = (const float*)&lds[(kt & 1) * 16384 + wm * 8192];
        #pragma unroll
        for (int m = 0; m < 4; ++m) {
            int r = m * 16 + lr;                         // row in half [0,64)
            const float* rowp = base + r * 64;
            #pragma unroll
            for (int ks = 0; ks < 2; ++ks) {
                int g0 = ks * 8 + lk * 2;                // logical granule pair
                f32x4 a = *(const f32x4*)(rowp + ((g0 ^ (r & 15)) << 2));
                f32x4 b2 = *(const f32x4*)(rowp + (((g0 + 1) ^ (r & 15)) << 2));
                bf16x8 v;
                v[0] = (short)f2bf(a[0]); v[1] = (short)f2bf(a[1]);
                v[2] = (short)f2bf(a[2]); v[3] = (short)f2bf(a[3]);
                v[4] = (short)f2bf(b2[0]); v[5] = (short)f2bf(b2[1]);
                v[6] = (short)f2bf(b2[2]); v[7] = (short)f2bf(b2[3]);
                af[m][ks] = v;
            }
        }
    };
    auto read_B2 = [&](int kt, int nh2, bf16x8 (&bfr)[2][2]) {   // n-frags {nh2*2, +1}
        #pragma unroll
        for (int n = 0; n < 2; ++n) {
            int rowb = wn * 64 + (nh2 * 2 + n) * 16 + lr;        // [0,256)
            const unsigned short* base =
                &lds[32768 + (kt & 1) * 16384 + (rowb >> 7) * 8192];
            int rl = rowb & 127;
            bfr[n][0] = *(const bf16x8*)(base + rl * 64 + cswz0);
            bfr[n][1] = *(const bf16x8*)(base + rl * 64 + cswz1);
        }
    };

    f32x4 acc[4][4] = {};

    // prologue: A[0](4) B[0](4) A[1](4); VMCNT(4) leaves A[1] in flight
    stage_A(0, 0); stage_A(0, 1);
    stage_B(0, 0); stage_B(0, 1);
    stage_A(1, 0); stage_A(1, 1);
    VMCNT(4);
    __builtin_amdgcn_s_barrier();
    __builtin_amdgcn_sched_barrier(0);

    for (int kt = 0; kt < NT; ++kt) {
        bf16x8 af[4][2], bfr[2][2];
        {   // p0: n-frags 0,1
            read_A(kt, af); read_B2(kt, 0, bfr);
            if (kt + 1 < NT) { stage_B(kt + 1, 0); stage_B(kt + 1, 1); }
            PHASE_MID();
            __builtin_amdgcn_s_setprio(1);
            #pragma unroll
            for (int m = 0; m < 4; ++m)
                #pragma unroll
                for (int n = 0; n < 2; ++n)
                    #pragma unroll
                    for (int ks = 0; ks < 2; ++ks)
                        acc[m][n] = __builtin_amdgcn_mfma_f32_16x16x32_bf16(
                            af[m][ks], bfr[n][ks], acc[m][n], 0, 0, 0);
            __builtin_amdgcn_s_setprio(0);
            PHASE_END();
        }
        {   // p1: n-frags 2,3 (af reused)
            bf16x8 bfr2[2][2];
            read_B2(kt, 1, bfr2);
            if (kt + 2 < NT) { stage_A(kt + 2, 0); stage_A(kt + 2, 1); }
            PHASE_MID();
            __builtin_amdgcn_s_setprio(1);
            #pragma unroll
            for (int m = 0; m < 4; ++m)
                #pragma unroll
                for (int n = 0; n < 2; ++n)
                    #pragma unroll
                    for (int ks = 0; ks < 2; ++ks)
                        acc[m][2 + n] = __builtin_amdgcn_mfma_f32_16x16x32_bf16(
                            af[m][ks], bfr2[n][ks], acc[m][2 + n], 0, 0, 0);
            __builtin_amdgcn_s_setprio(0);
            if (kt + 2 < NT)      { VMCNT(4); }   // drains A[kt+1]+B[kt+1]
            else if (kt + 1 < NT) { VMCNT(0); }   // tail: drain tile NT-1
            PHASE_END();
        }
    }

    #pragma unroll
    for (int m = 0; m < 4; ++m)
        #pragma unroll
        for (int n = 0; n < 4; ++n)
            #pragma unroll
            for (int r = 0; r < 4; ++r) {
                int row = m0 + wm * 64 + m * 16 + lk * 4 + r;
                int col = n0 + wn * 64 + n * 16 + lr;
                float v = acc[m][n][r];
                v = v / (1.0f + __expf(-v));
                C[(size_t)row * N + col] = f2bf(v);
            }
}

// ---------------- GEMM2: out = P @ Vsub, M=8192 N=4096 K=1024 ----------------
// R6/R9-proven 4-quadrant schedule (16 MFMA/phase), 256x256, T1 swizzle, 0 conflicts.
__global__ __launch_bounds__(512, 2)
void gemm2_8p(const unsigned short* __restrict__ A, const unsigned short* __restrict__ Bt,
              float* __restrict__ C) {
    constexpr int K = K_SUB, N = D_MODEL, NT = K / 64;   // NT=16
    constexpr int BUFSZ = 32768;
    __shared__ __align__(16) unsigned short lds[2 * BUFSZ];   // 128 KB

    const int t = threadIdx.x, lane = t & 63, w = t >> 6;
    const int wr = w >> 2, wc = w & 3;
    const int lr = lane & 15, lk = lane >> 4;

    const int f = blockIdx.x;
    const int g = (f & 7) * 64 + (f >> 3);
    const int m0 = (g >> 4) * 256, n0 = (g & 15) * 256;

    const int cswz0 = ((lk ^ (lr & 7)) * 8);
    const int cswz1 = (((4 + lk) ^ (lr & 7)) * 8);
    const int srow = lane >> 3;
    const int scol = ((lane & 7) ^ srow) * 8;

    auto stage_A = [&](int kt, int mh) {
        const unsigned short* src = A + (size_t)(m0 + mh * 128) * K + kt * 64;
        unsigned short* dst = &lds[(kt & 1) * BUFSZ + mh * 8192];
        #pragma unroll
        for (int i = 0; i < 2; ++i) {
            int c2 = i * 8 + w;
            gload_lds16(src + (size_t)(c2 * 8 + srow) * K + scol, dst + c2 * 512);
        }
    };
    auto stage_B = [&](int kt, int nh) {
        const unsigned short* src = Bt + (size_t)(n0 + nh * 128) * K + kt * 64;
        unsigned short* dst = &lds[(kt & 1) * BUFSZ + 16384 + nh * 8192];
        #pragma unroll
        for (int i = 0; i < 2; ++i) {
            int c2 = i * 8 + w;
            gload_lds16(src + (size_t)(c2 * 8 + srow) * K + scol, dst + c2 * 512);
        }
    };
    auto read_A = [&](int kt, int mh, bf16x8 (&af)[4][2]) {
        const unsigned short* base = &lds[(kt & 1) * BUFSZ + mh * 8192];
        #pragma unroll
        for (int m = 0; m < 4; ++m) {
            int rw = wr * 64 + m * 16 + lr;
            af[m][0] = *(const bf16x8*)(base + rw * 64 + cswz0);
            af[m][1] = *(const bf16x8*)(base + rw * 64 + cswz1);
        }
    };
    auto read_B = [&](int kt, int nh, bf16x8 (&bfr)[2][2]) {
        const unsigned short* base = &lds[(kt & 1) * BUFSZ + 16384 + nh * 8192];
        #pragma unroll
        for (int n = 0; n < 2; ++n) {
            int rw = wc * 32 + n * 16 + lr;
            bfr[n][0] = *(const bf16x8*)(base + rw * 64 + cswz0);
            bfr[n][1] = *(const bf16x8*)(base + rw * 64 + cswz1);
        }
    };

    f32x4 acc[8][4] = {};

    stage_A(0, 0); stage_B(0, 0); stage_B(0, 1); stage_A(0, 1);
    stage_A(1, 0); stage_B(1, 1); stage_A(1, 1);
    VMCNT(6);
    __builtin_amdgcn_s_barrier();
    __builtin_amdgcn_sched_barrier(0);

    for (int kt = 0; kt < NT; ++kt) {
        bf16x8 af[4][2], bf0[2][2], bf1[2][2];
        {   // p0: quadrant (0,0)
            read_A(kt, 0, af); read_B(kt, 0, bf0);
            if (kt + 1 < NT) stage_B(kt + 1, 0);
            PHASE_MID();
            __builtin_amdgcn_s_setprio(1);
            #pragma unroll
            for (int m = 0; m < 4; ++m)
                #pragma unroll
                for (int n = 0; n < 2; ++n)
                    #pragma unroll
                    for (int ks = 0; ks < 2; ++ks)
                        acc[m][n] = __builtin_amdgcn_mfma_f32_16x16x32_bf16(
                            af[m][ks], bf0[n][ks], acc[m][n], 0, 0, 0);
            __builtin_amdgcn_s_setprio(0);
            PHASE_END();
        }
        {   // p1: quadrant (0,1)
            read_B(kt, 1, bf1);
            if (kt + 2 < NT) stage_A(kt + 2, 0);
            PHASE_MID();
            __builtin_amdgcn_s_setprio(1);
            #pragma unroll
            for (int m = 0; m < 4; ++m)
                #pragma unroll
                for (int n = 0; n < 2; ++n)
                    #pragma unroll
                    for (int ks = 0; ks < 2; ++ks)
                        acc[m][2 + n] = __builtin_amdgcn_mfma_f32_16x16x32_bf16(
                            af[m][ks], bf1[n][ks], acc[m][2 + n], 0, 0, 0);
            __builtin_amdgcn_s_setprio(0);
            PHASE_END();
        }
        {   // p2: quadrant (1,0)
            read_A(kt, 1, af);
            if (kt + 2 < NT) stage_B(kt + 2, 1);
            PHASE_MID();
            __builtin_amdgcn_s_setprio(1);
            #pragma unroll
            for (int m = 0; m < 4; ++m)
                #pragma unroll
                for (int n = 0; n < 2; ++n)
                    #pragma unroll
                    for (int ks = 0; ks < 2; ++ks)
                        acc[4 + m][n] = __builtin_amdgcn_mfma_f32_16x16x32_bf16(
                            af[m][ks], bf0[n][ks], acc[4 + m][n], 0, 0, 0);
            __builtin_amdgcn_s_setprio(0);
            PHASE_END();
        }
        {   // p3: quadrant (1,1)
            if (kt + 2 < NT) stage_A(kt + 2, 1);
            PHASE_MID();
            __builtin_amdgcn_s_setprio(1);
            #pragma unroll
            for (int m = 0; m < 4; ++m)
                #pragma unroll
                for (int n = 0; n < 2; ++n)
                    #pragma unroll
                    for (int ks = 0; ks < 2; ++ks)
                        acc[4 + m][2 + n] = __builtin_amdgcn_mfma_f32_16x16x32_bf16(
                            af[m][ks], bf1[n][ks], acc[4 + m][2 + n], 0, 0, 0);
            __builtin_amdgcn_s_setprio(0);
            __builtin_amdgcn_sched_barrier(0);
            if (kt < NT - 2) { VMCNT(6); }
            else if (kt == NT - 2) { VMCNT(0); }
            PHASE_END();
        }
    }

    #pragma unroll
    for (int mh = 0; mh < 2; ++mh)
        #pragma unroll
        for (int nh = 0; nh < 2; ++nh)
            #pragma unroll
            for (int m = 0; m < 4; ++m)
                #pragma unroll
                for (int n = 0; n < 2; ++n)
                    #pragma unroll
                    for (int r = 0; r < 4; ++r) {
                        int row = m0 + mh * 128 + wr * 64 + m * 16 + lk * 4 + r;
                        int col = n0 + nh * 128 + wc * 32 + n * 16 + lr;
                        C[(size_t)row * N + col] = acc[mh * 4 + m][nh * 2 + n][r];
                    }
}

extern "C" void kernel_launch(void* const* d_in, const int* in_sizes, int n_in,
                              void* d_out, int out_size, void* d_ws, size_t ws_size,
                              hipStream_t stream) {
    const float* x   = (const float*)d_in[0];
    const int*   idx = (const int*)d_in[1];
    const float* U   = (const float*)d_in[2];
    const float* V   = (const float*)d_in[3];
    float* out = (float*)d_out;

    unsigned short* Ut = (unsigned short*)d_ws;                 // [K_SUB][D_MODEL] bf16
    unsigned short* Vt = Ut + (size_t)K_SUB * D_MODEL;          // [D_MODEL][K_SUB] bf16
    unsigned short* P  = Vt + (size_t)K_SUB * D_MODEL;          // [N_TOK][K_SUB]  bf16

    gathers_k<<<2048 + 1024, 256, 0, stream>>>(idx, U, V, Ut, Vt);
    gemm1_f32a<<<256, 512, 0, stream>>>(x, Ut, P);
    gemm2_8p<<<512, 512, 0, stream>>>(P, Vt, out);
}

// Round 16
// 226.127 us; speedup vs baseline: 1.0376x; 1.0376x over previous
//
#include <hip/hip_runtime.h>
#include <hip/hip_bf16.h>
#include <stdint.h>

#define D_MODEL 4096
#define D_BASE  8192
#define K_SUB   1024
#define N_TOK   8192

typedef __attribute__((ext_vector_type(8))) short bf16x8;
typedef __attribute__((ext_vector_type(4))) float f32x4;

__device__ __forceinline__ unsigned short f2bf(float f) {
    union { float f; uint32_t u; } c; c.f = f;
    uint32_t u = c.u;
    uint32_t r = u + 0x7FFFu + ((u >> 16) & 1u);   // round-to-nearest-even
    return (unsigned short)(r >> 16);
}

__device__ __forceinline__ void gload_lds16(const void* g, void* l) {
    __builtin_amdgcn_global_load_lds(
        (__attribute__((address_space(1))) void*)g,
        (__attribute__((address_space(3))) void*)l, 16, 0, 0);
}

// De-pinned phase fences (m141: sched_barrier(0) order-pinning cost −42% on the
// m97 kernel; rule #18 only applies to inline-asm ds_reads, ours are compiler
// loads). "memory" clobber still orders all memory ops; consumers pin reads.
#define VMCNT(N) asm volatile("s_waitcnt vmcnt(" #N ")" ::: "memory")
#define PHASE_MID() do { __builtin_amdgcn_s_barrier(); \
    asm volatile("s_waitcnt lgkmcnt(0)" ::: "memory"); } while (0)
#define PHASE_END() __builtin_amdgcn_s_barrier()

// ---------------- Fused prep (R9-exact: scatter-first ranges) ----------------
//   b in [0,512):      gather_u — 8 k-rows x 1024 n, row-local scatter reads,
//                      LDS mini-transpose, 16B-run writes
//   b in [512,1536):   gather_v — 64x64 LDS transpose
//   b in [1536,17920): convert_x — f32->bf16 stream (backfills CUs)
__global__ __launch_bounds__(256) void prep_fused(const float* __restrict__ x,
                                                  const int* __restrict__ idx,
                                                  const float* __restrict__ U,
                                                  const float* __restrict__ V,
                                                  unsigned short* __restrict__ xb,
                                                  unsigned short* __restrict__ Ut,
                                                  unsigned short* __restrict__ Vt) {
    __shared__ __align__(16) char smem[24576];
    const int b = blockIdx.x;
    const int t = threadIdx.x;
    if (b < 512) {
        unsigned short* tile = (unsigned short*)smem;   // [1024][12]
        const int k0 = b * 8;
        #pragma unroll
        for (int c = 0; c < 4; ++c) {
            int n = c * 256 + t;
            int col = idx[n];
            const float* Ucol = U + (size_t)k0 * D_BASE + col;
            #pragma unroll
            for (int kr = 0; kr < 8; ++kr)
                tile[n * 12 + kr] = f2bf(Ucol[(size_t)kr * D_BASE]);
        }
        __syncthreads();
        #pragma unroll
        for (int c = 0; c < 4; ++c) {
            int n = c * 256 + t;
            ushort4 a = *(const ushort4*)&tile[n * 12];
            ushort4 q = *(const ushort4*)&tile[n * 12 + 4];
            *(ushort4*)(Ut + (size_t)n * D_MODEL + k0) = a;
            *(ushort4*)(Ut + (size_t)n * D_MODEL + k0 + 4) = q;
        }
    } else if (b < 1536) {
        unsigned short (*tile)[66] = (unsigned short(*)[66])smem;   // 64x66
        int* lidx = (int*)(smem + 64 * 66 * 2);
        const int bx = b - 512;
        const int n0 = (bx & 15) * 64;
        const int d0 = (bx >> 4) * 64;
        if (t < 64) lidx[t] = idx[n0 + t];
        __syncthreads();
        const int c = t & 63, r4 = t >> 6;
        #pragma unroll
        for (int p = 0; p < 16; ++p) {
            int nr = p * 4 + r4;
            tile[nr][c] = f2bf(V[(size_t)lidx[nr] * D_MODEL + d0 + c]);
        }
        __syncthreads();
        #pragma unroll
        for (int p = 0; p < 16; ++p) {
            int dr = p * 4 + r4;
            Vt[(size_t)(d0 + dr) * K_SUB + n0 + c] = tile[c][dr];
        }
    } else {
        const int cb = b - 1536;
        int e = cb * 256 + t;
        const float4* p = (const float4*)x + (size_t)e * 2;
        float4 a = p[0], q = p[1];
        ushort4 lo, hi;
        lo.x = f2bf(a.x); lo.y = f2bf(a.y); lo.z = f2bf(a.z); lo.w = f2bf(a.w);
        hi.x = f2bf(q.x); hi.y = f2bf(q.y); hi.z = f2bf(q.z); hi.w = f2bf(q.w);
        *(ushort4*)(xb + (size_t)e * 8) = lo;
        *(ushort4*)(xb + (size_t)e * 8 + 4) = hi;
    }
}

// ---------------- GEMM1: P = silu(xb @ Usub), M=8192 N=1024 K=4096 ----------------
// R9-exact structure: BM=256 BN=128 BK=64, 8 waves 4M x 2N, 16x16x32 MFMA.
// 4 phases / 2 K-tiles; stages p0:{A1[T+1],B[T+1]} p1:{A0[T+2]} p2:{A1[T+2],B[T+2]}
// p3:{A0[T+3]}; waits end-p1 vmcnt(2) (0 at tail), end-p3 vmcnt(2).
__global__ __launch_bounds__(512, 2)
void gemm1_8p(const unsigned short* __restrict__ A, const unsigned short* __restrict__ Bt,
              unsigned short* __restrict__ C) {
    constexpr int K = D_MODEL, N = K_SUB, NT = K / 64;   // NT=64 (even)
    __shared__ __align__(16) unsigned short lds[49152];  // 96 KB

    const int t = threadIdx.x, lane = t & 63, w = t >> 6;
    const int wm = w >> 1, wn = w & 1;                   // 4M x 2N
    const int lr = lane & 15, lk = lane >> 4;

    const int f = blockIdx.x;
    const int g = (f & 7) * 32 + (f >> 3);
    const int m0 = (g >> 3) * 256, n0 = (g & 7) * 128;

    const int cswz0 = ((lk ^ (lr & 7)) * 8);
    const int cswz1 = (((4 + lk) ^ (lr & 7)) * 8);
    const int srow = lane >> 3;
    const int scol = ((lane & 7) ^ srow) * 8;

    auto stage_A = [&](int kt, int half) {
        const unsigned short* src = A + (size_t)(m0 + half * 128) * K + kt * 64;
        unsigned short* dst = &lds[(kt & 1) * 24576 + half * 8192];
        #pragma unroll
        for (int i = 0; i < 2; ++i) {
            int c2 = i * 8 + w;
            gload_lds16(src + (size_t)(c2 * 8 + srow) * K + scol, dst + c2 * 512);
        }
    };
    auto stage_B = [&](int kt) {
        const unsigned short* src = Bt + (size_t)n0 * K + kt * 64;
        unsigned short* dst = &lds[(kt & 1) * 24576 + 16384];
        #pragma unroll
        for (int i = 0; i < 2; ++i) {
            int c2 = i * 8 + w;
            gload_lds16(src + (size_t)(c2 * 8 + srow) * K + scol, dst + c2 * 512);
        }
    };
    auto read_A = [&](int kt, bf16x8 (&af)[4][2]) {
        const unsigned short* base = &lds[(kt & 1) * 24576 + (wm >> 1) * 8192];
        #pragma unroll
        for (int m = 0; m < 4; ++m) {
            int rw = (wm & 1) * 64 + m * 16 + lr;
            af[m][0] = *(const bf16x8*)(base + rw * 64 + cswz0);
            af[m][1] = *(const bf16x8*)(base + rw * 64 + cswz1);
        }
    };
    auto read_B2 = [&](int kt, int nh, bf16x8 (&bfr)[2][2]) {
        const unsigned short* base = &lds[(kt & 1) * 24576 + 16384];
        #pragma unroll
        for (int n = 0; n < 2; ++n) {
            int rw = wn * 64 + (nh * 2 + n) * 16 + lr;
            bfr[n][0] = *(const bf16x8*)(base + rw * 64 + cswz0);
            bfr[n][1] = *(const bf16x8*)(base + rw * 64 + cswz1);
        }
    };

    f32x4 acc[4][4] = {};

    stage_A(0, 0); stage_A(0, 1); stage_B(0); stage_A(1, 0);
    VMCNT(2);
    __builtin_amdgcn_s_barrier();

    for (int kt = 0; kt < NT; kt += 2) {
        const bool more = (kt + 2 < NT);
        {   // p0: tile kt, n-frags 0,1
            bf16x8 af[4][2], bfr[2][2];
            read_A(kt, af); read_B2(kt, 0, bfr);
            stage_A(kt + 1, 1); stage_B(kt + 1);
            PHASE_MID();
            __builtin_amdgcn_s_setprio(1);
            #pragma unroll
            for (int m = 0; m < 4; ++m)
                #pragma unroll
                for (int n = 0; n < 2; ++n)
                    #pragma unroll
                    for (int ks = 0; ks < 2; ++ks)
                        acc[m][n] = __builtin_amdgcn_mfma_f32_16x16x32_bf16(
                            af[m][ks], bfr[n][ks], acc[m][n], 0, 0, 0);
            __builtin_amdgcn_s_setprio(0);
            PHASE_END();
            // p1: tile kt, n-frags 2,3 (af reused)
            bf16x8 bfr2[2][2];
            read_B2(kt, 1, bfr2);
            if (more) stage_A(kt + 2, 0);
            PHASE_MID();
            __builtin_amdgcn_s_setprio(1);
            #pragma unroll
            for (int m = 0; m < 4; ++m)
                #pragma unroll
                for (int n = 0; n < 2; ++n)
                    #pragma unroll
                    for (int ks = 0; ks < 2; ++ks)
                        acc[m][2 + n] = __builtin_amdgcn_mfma_f32_16x16x32_bf16(
                            af[m][ks], bfr2[n][ks], acc[m][2 + n], 0, 0, 0);
            __builtin_amdgcn_s_setprio(0);
            if (more) { VMCNT(2); } else { VMCNT(0); }
            PHASE_END();
        }
        {   // p2: tile kt+1, n-frags 0,1
            bf16x8 af[4][2], bfr[2][2];
            read_A(kt + 1, af); read_B2(kt + 1, 0, bfr);
            if (more) { stage_A(kt + 2, 1); stage_B(kt + 2); }
            PHASE_MID();
            __builtin_amdgcn_s_setprio(1);
            #pragma unroll
            for (int m = 0; m < 4; ++m)
                #pragma unroll
                for (int n = 0; n < 2; ++n)
                    #pragma unroll
                    for (int ks = 0; ks < 2; ++ks)
                        acc[m][n] = __builtin_amdgcn_mfma_f32_16x16x32_bf16(
                            af[m][ks], bfr[n][ks], acc[m][n], 0, 0, 0);
            __builtin_amdgcn_s_setprio(0);
            PHASE_END();
            // p3: tile kt+1, n-frags 2,3
            bf16x8 bfr2[2][2];
            read_B2(kt + 1, 1, bfr2);
            if (more) stage_A(kt + 3, 0);
            PHASE_MID();
            __builtin_amdgcn_s_setprio(1);
            #pragma unroll
            for (int m = 0; m < 4; ++m)
                #pragma unroll
                for (int n = 0; n < 2; ++n)
                    #pragma unroll
                    for (int ks = 0; ks < 2; ++ks)
                        acc[m][2 + n] = __builtin_amdgcn_mfma_f32_16x16x32_bf16(
                            af[m][ks], bfr2[n][ks], acc[m][2 + n], 0, 0, 0);
            __builtin_amdgcn_s_setprio(0);
            if (more) VMCNT(2);
            PHASE_END();
        }
    }

    #pragma unroll
    for (int m = 0; m < 4; ++m)
        #pragma unroll
        for (int n = 0; n < 4; ++n)
            #pragma unroll
            for (int r = 0; r < 4; ++r) {
                int row = m0 + wm * 64 + m * 16 + lk * 4 + r;
                int col = n0 + wn * 64 + n * 16 + lr;
                float v = acc[m][n][r];
                v = v / (1.0f + __expf(-v));
                C[(size_t)row * N + col] = f2bf(v);
            }
}

// ---------------- GEMM2: out = P @ Vsub, M=8192 N=4096 K=1024 ----------------
// R9-exact 4-quadrant schedule (16 MFMA/phase), 256x256, T1 swizzle, 0 conflicts.
__global__ __launch_bounds__(512, 2)
void gemm2_8p(const unsigned short* __restrict__ A, const unsigned short* __restrict__ Bt,
              float* __restrict__ C) {
    constexpr int K = K_SUB, N = D_MODEL, NT = K / 64;   // NT=16
    constexpr int BUFSZ = 32768;
    __shared__ __align__(16) unsigned short lds[2 * BUFSZ];   // 128 KB

    const int t = threadIdx.x, lane = t & 63, w = t >> 6;
    const int wr = w >> 2, wc = w & 3;
    const int lr = lane & 15, lk = lane >> 4;

    const int f = blockIdx.x;
    const int g = (f & 7) * 64 + (f >> 3);
    const int m0 = (g >> 4) * 256, n0 = (g & 15) * 256;

    const int cswz0 = ((lk ^ (lr & 7)) * 8);
    const int cswz1 = (((4 + lk) ^ (lr & 7)) * 8);
    const int srow = lane >> 3;
    const int scol = ((lane & 7) ^ srow) * 8;

    auto stage_A = [&](int kt, int mh) {
        const unsigned short* src = A + (size_t)(m0 + mh * 128) * K + kt * 64;
        unsigned short* dst = &lds[(kt & 1) * BUFSZ + mh * 8192];
        #pragma unroll
        for (int i = 0; i < 2; ++i) {
            int c2 = i * 8 + w;
            gload_lds16(src + (size_t)(c2 * 8 + srow) * K + scol, dst + c2 * 512);
        }
    };
    auto stage_B = [&](int kt, int nh) {
        const unsigned short* src = Bt + (size_t)(n0 + nh * 128) * K + kt * 64;
        unsigned short* dst = &lds[(kt & 1) * BUFSZ + 16384 + nh * 8192];
        #pragma unroll
        for (int i = 0; i < 2; ++i) {
            int c2 = i * 8 + w;
            gload_lds16(src + (size_t)(c2 * 8 + srow) * K + scol, dst + c2 * 512);
        }
    };
    auto read_A = [&](int kt, int mh, bf16x8 (&af)[4][2]) {
        const unsigned short* base = &lds[(kt & 1) * BUFSZ + mh * 8192];
        #pragma unroll
        for (int m = 0; m < 4; ++m) {
            int rw = wr * 64 + m * 16 + lr;
            af[m][0] = *(const bf16x8*)(base + rw * 64 + cswz0);
            af[m][1] = *(const bf16x8*)(base + rw * 64 + cswz1);
        }
    };
    auto read_B = [&](int kt, int nh, bf16x8 (&bfr)[2][2]) {
        const unsigned short* base = &lds[(kt & 1) * BUFSZ + 16384 + nh * 8192];
        #pragma unroll
        for (int n = 0; n < 2; ++n) {
            int rw = wc * 32 + n * 16 + lr;
            bfr[n][0] = *(const bf16x8*)(base + rw * 64 + cswz0);
            bfr[n][1] = *(const bf16x8*)(base + rw * 64 + cswz1);
        }
    };

    f32x4 acc[8][4] = {};

    stage_A(0, 0); stage_B(0, 0); stage_B(0, 1); stage_A(0, 1);
    stage_A(1, 0); stage_B(1, 1); stage_A(1, 1);
    VMCNT(6);
    __builtin_amdgcn_s_barrier();

    for (int kt = 0; kt < NT; ++kt) {
        bf16x8 af[4][2], bf0[2][2], bf1[2][2];
        {   // p0: quadrant (0,0)
            read_A(kt, 0, af); read_B(kt, 0, bf0);
            if (kt + 1 < NT) stage_B(kt + 1, 0);
            PHASE_MID();
            __builtin_amdgcn_s_setprio(1);
            #pragma unroll
            for (int m = 0; m < 4; ++m)
                #pragma unroll
                for (int n = 0; n < 2; ++n)
                    #pragma unroll
                    for (int ks = 0; ks < 2; ++ks)
                        acc[m][n] = __builtin_amdgcn_mfma_f32_16x16x32_bf16(
                            af[m][ks], bf0[n][ks], acc[m][n], 0, 0, 0);
            __builtin_amdgcn_s_setprio(0);
            PHASE_END();
        }
        {   // p1: quadrant (0,1)
            read_B(kt, 1, bf1);
            if (kt + 2 < NT) stage_A(kt + 2, 0);
            PHASE_MID();
            __builtin_amdgcn_s_setprio(1);
            #pragma unroll
            for (int m = 0; m < 4; ++m)
                #pragma unroll
                for (int n = 0; n < 2; ++n)
                    #pragma unroll
                    for (int ks = 0; ks < 2; ++ks)
                        acc[m][2 + n] = __builtin_amdgcn_mfma_f32_16x16x32_bf16(
                            af[m][ks], bf1[n][ks], acc[m][2 + n], 0, 0, 0);
            __builtin_amdgcn_s_setprio(0);
            PHASE_END();
        }
        {   // p2: quadrant (1,0)
            read_A(kt, 1, af);
            if (kt + 2 < NT) stage_B(kt + 2, 1);
            PHASE_MID();
            __builtin_amdgcn_s_setprio(1);
            #pragma unroll
            for (int m = 0; m < 4; ++m)
                #pragma unroll
                for (int n = 0; n < 2; ++n)
                    #pragma unroll
                    for (int ks = 0; ks < 2; ++ks)
                        acc[4 + m][n] = __builtin_amdgcn_mfma_f32_16x16x32_bf16(
                            af[m][ks], bf0[n][ks], acc[4 + m][n], 0, 0, 0);
            __builtin_amdgcn_s_setprio(0);
            PHASE_END();
        }
        {   // p3: quadrant (1,1)
            if (kt + 2 < NT) stage_A(kt + 2, 1);
            PHASE_MID();
            __builtin_amdgcn_s_setprio(1);
            #pragma unroll
            for (int m = 0; m < 4; ++m)
                #pragma unroll
                for (int n = 0; n < 2; ++n)
                    #pragma unroll
                    for (int ks = 0; ks < 2; ++ks)
                        acc[4 + m][2 + n] = __builtin_amdgcn_mfma_f32_16x16x32_bf16(
                            af[m][ks], bf1[n][ks], acc[4 + m][2 + n], 0, 0, 0);
            __builtin_amdgcn_s_setprio(0);
            if (kt < NT - 2) { VMCNT(6); }
            else if (kt == NT - 2) { VMCNT(0); }
            PHASE_END();
        }
    }

    #pragma unroll
    for (int mh = 0; mh < 2; ++mh)
        #pragma unroll
        for (int nh = 0; nh < 2; ++nh)
            #pragma unroll
            for (int m = 0; m < 4; ++m)
                #pragma unroll
                for (int n = 0; n < 2; ++n)
                    #pragma unroll
                    for (int r = 0; r < 4; ++r) {
                        int row = m0 + mh * 128 + wr * 64 + m * 16 + lk * 4 + r;
                        int col = n0 + nh * 128 + wc * 32 + n * 16 + lr;
                        C[(size_t)row * N + col] = acc[mh * 4 + m][nh * 2 + n][r];
                    }
}

extern "C" void kernel_launch(void* const* d_in, const int* in_sizes, int n_in,
                              void* d_out, int out_size, void* d_ws, size_t ws_size,
                              hipStream_t stream) {
    const float* x   = (const float*)d_in[0];
    const int*   idx = (const int*)d_in[1];
    const float* U   = (const float*)d_in[2];
    const float* V   = (const float*)d_in[3];
    float* out = (float*)d_out;

    unsigned short* Ut = (unsigned short*)d_ws;                 // [K_SUB][D_MODEL] bf16
    unsigned short* Vt = Ut + (size_t)K_SUB * D_MODEL;          // [D_MODEL][K_SUB] bf16
    unsigned short* P  = Vt + (size_t)K_SUB * D_MODEL;          // [N_TOK][K_SUB]  bf16
    unsigned short* xb = (unsigned short*)d_out;                // [N_TOK][D_MODEL] bf16 (temp)

    prep_fused<<<512 + 1024 + 16384, 256, 0, stream>>>(x, idx, U, V, xb, Ut, Vt);
    gemm1_8p<<<256, 512, 0, stream>>>(xb, Ut, P);
    gemm2_8p<<<512, 512, 0, stream>>>(P, Vt, out);
}